// Round 2
// baseline (187.031 us; speedup 1.0000x reference)
//
#include <hip/hip_runtime.h>
#include <hip/hip_bf16.h>

// SelfAttentionBlock: B=4, C=256, RC=128, H=W=64 (N=4096)
// Pipeline: k_cvtw (weights->bf16) -> k_qkv (Q,K,V^T bf16) -> k_attn (flash) -> k_out (proj+residual)
// Round 2: k_attn rewritten — 8 waves/block, in-block split-KV (2 groups x 32 tiles),
//          register-staged K/V prefetch, DPP-based softmax reductions.

#define B_   4
#define C_   256
#define RC_  128
#define N_   4096
#define SCALE 0.08838834764831845f  // 1/sqrt(128)

typedef __bf16 bf16x8 __attribute__((ext_vector_type(8)));
typedef unsigned short u16x8 __attribute__((ext_vector_type(8)));
typedef float f32x4 __attribute__((ext_vector_type(4)));

static __device__ __forceinline__ unsigned short f2bf(float f) {
    unsigned int u = __builtin_bit_cast(unsigned int, f);
    u += 0x7fffu + ((u >> 16) & 1u);   // round-to-nearest-even
    return (unsigned short)(u >> 16);
}

static __device__ __forceinline__ f32x4 mfma16(u16x8 a, u16x8 b, f32x4 c) {
    return __builtin_amdgcn_mfma_f32_16x16x32_bf16(
        __builtin_bit_cast(bf16x8, a), __builtin_bit_cast(bf16x8, b), c, 0, 0, 0);
}

// DPP cross-lane (within 16-lane rows; our reduce groups are exactly lanes [g*16, g*16+16))
template<int CTRL>
static __device__ __forceinline__ float dppf(float x) {
    int r = __builtin_amdgcn_update_dpp(0, __builtin_bit_cast(int, x), CTRL, 0xf, 0xf, true);
    return __builtin_bit_cast(float, r);
}
static __device__ __forceinline__ float red16_max(float v) {
    v = fmaxf(v, dppf<0xB1>(v));   // quad_perm [1,0,3,2]  = xor 1
    v = fmaxf(v, dppf<0x4E>(v));   // quad_perm [2,3,0,1]  = xor 2
    v = fmaxf(v, dppf<0x124>(v));  // row_ror:4
    v = fmaxf(v, dppf<0x128>(v));  // row_ror:8
    return v;
}
static __device__ __forceinline__ float red16_sum(float v) {
    v += dppf<0xB1>(v);
    v += dppf<0x4E>(v);
    v += dppf<0x124>(v);
    v += dppf<0x128>(v);
    return v;
}

// ---------------- kernel 0: convert weights to bf16 ----------------
__global__ __launch_bounds__(256) void k_cvtw(
    const float* __restrict__ wq, const float* __restrict__ wk,
    const float* __restrict__ wv, const float* __restrict__ wo,
    unsigned short* __restrict__ ws)
{
    int i = blockIdx.x * 256 + threadIdx.x;  // 0..131071
    const float* src; int off;
    if (i < 32768)       { src = wq; off = 0; }
    else if (i < 65536)  { src = wk; off = 32768; }
    else if (i < 98304)  { src = wv; off = 65536; }
    else                 { src = wo; off = 98304; }
    int j = i - off;
    ws[off + j] = f2bf(src[j]);
}

// ---------------- kernel 1: QKV projection ----------------
#define K1_LDA 264  // 256 + 8 pad (shorts)

__global__ __launch_bounds__(256) void k_qkv(
    const float* __restrict__ x, const unsigned short* __restrict__ wbf,
    const float* __restrict__ bq, const float* __restrict__ bk, const float* __restrict__ bv,
    unsigned short* __restrict__ Qb, unsigned short* __restrict__ Kb,
    unsigned short* __restrict__ Vt)
{
    __shared__ unsigned short lds[64 * K1_LDA];
    const int b  = blockIdx.y;
    const int n0 = blockIdx.x * 64;
    const int t  = threadIdx.x;
    const int lane = t & 63, wv_ = t >> 6;
    const int g = lane >> 4, q16 = lane & 15;

    {
        const float* xb = x + ((size_t)b * C_ * N_) + n0 + lane;
        #pragma unroll
        for (int it = 0; it < 8; ++it) {
            int c0 = wv_ * 64 + it * 8;
            u16x8 v;
            #pragma unroll
            for (int e = 0; e < 8; ++e)
                v[e] = f2bf(xb[(size_t)(c0 + e) * N_]);
            *(u16x8*)&lds[lane * K1_LDA + c0] = v;
        }
    }
    __syncthreads();

    f32x4 acc[3][2][4];
    #pragma unroll
    for (int tq = 0; tq < 3; ++tq)
        #pragma unroll
        for (int r2 = 0; r2 < 2; ++r2)
            #pragma unroll
            for (int nf = 0; nf < 4; ++nf)
                acc[tq][r2][nf] = (f32x4){0.f, 0.f, 0.f, 0.f};

    const int rbase = wv_ * 32;
    #pragma unroll
    for (int ks = 0; ks < 8; ++ks) {
        u16x8 a[4];
        #pragma unroll
        for (int nf = 0; nf < 4; ++nf)
            a[nf] = *(const u16x8*)&lds[(nf * 16 + q16) * K1_LDA + ks * 32 + g * 8];
        #pragma unroll
        for (int tq = 0; tq < 3; ++tq) {
            const unsigned short* w = wbf + tq * 32768;
            #pragma unroll
            for (int r2 = 0; r2 < 2; ++r2) {
                u16x8 bf = *(const u16x8*)&w[(size_t)(rbase + r2 * 16 + q16) * 256 + ks * 32 + g * 8];
                #pragma unroll
                for (int nf = 0; nf < 4; ++nf)
                    acc[tq][r2][nf] = mfma16(a[nf], bf, acc[tq][r2][nf]);
            }
        }
    }

    #pragma unroll
    for (int r2 = 0; r2 < 2; ++r2) {
        int r = rbase + r2 * 16 + q16;
        float biasq = bq[r], biask = bk[r];
        #pragma unroll
        for (int nf = 0; nf < 4; ++nf) {
            #pragma unroll
            for (int i = 0; i < 4; ++i) {
                int n = n0 + nf * 16 + g * 4 + i;
                size_t idx = ((size_t)b * N_ + n) * RC_ + r;
                Qb[idx] = f2bf((acc[0][r2][nf][i] + biasq) * SCALE);
                Kb[idx] = f2bf(acc[1][r2][nf][i] + biask);
            }
        }
    }

    __syncthreads();
    #pragma unroll
    for (int r2 = 0; r2 < 2; ++r2) {
        int r = rbase + r2 * 16 + q16;
        float biasv = bv[r];
        #pragma unroll
        for (int nf = 0; nf < 4; ++nf)
            #pragma unroll
            for (int i = 0; i < 4; ++i)
                lds[r * 72 + nf * 16 + g * 4 + i] = f2bf(acc[2][r2][nf][i] + biasv);
    }
    __syncthreads();
    #pragma unroll
    for (int it = 0; it < 4; ++it) {
        int r = it * 32 + (t >> 3);
        int s = (t & 7) * 8;
        u16x8 v = *(const u16x8*)&lds[r * 72 + s];
        *(u16x8*)&Vt[((size_t)b * RC_ + r) * N_ + n0 + s] = v;
    }
}

// ---------------- kernel 2: flash attention (8 waves, split-KV, prefetch) ----------------
#define QS 136  // 128 + 8 pad (shorts), 272B stride
#define VS 72   // 64 + 8 pad (shorts), 144B stride

__global__ __launch_bounds__(512, 2) void k_attn(
    const unsigned short* __restrict__ Qb, const unsigned short* __restrict__ Kb,
    const unsigned short* __restrict__ Vt, unsigned short* __restrict__ Ob)
{
    __shared__ unsigned short Ql[64 * QS];        // 17408 B
    __shared__ unsigned short Kl[2][64 * QS];     // 34816 B (per KV-group)
    __shared__ unsigned short Vl[2][128 * VS];    // 36864 B
    __shared__ unsigned short Pl[8 * 16 * VS];    // 18432 B (per-wave P)

    const int b  = blockIdx.y;
    const int n0 = blockIdx.x * 64;
    const int t  = threadIdx.x;
    const int lane = t & 63, wv_ = t >> 6;        // 8 waves
    const int wg  = wv_ >> 2;                     // KV half (0: tiles 0-31, 1: 32-63)
    const int wig = wv_ & 3;                      // q-row group (16 rows each)
    const int g = lane >> 4, q16 = lane & 15;
    const int tg = t & 255;                       // thread id within KV group

    // stage Q tile (all 512 threads): 64 rows x 16 chunks of 16B
    {
        const unsigned short* src = Qb + ((size_t)b * N_ + n0) * RC_;
        #pragma unroll
        for (int j = 0; j < 2; ++j) {
            int c = t + j * 512;
            int row = c >> 4, off = (c & 15) * 8;
            *(u16x8*)&Ql[row * QS + off] = *(const u16x8*)&src[row * RC_ + off];
        }
    }

    const unsigned short* Kbase = Kb + (size_t)b * N_ * RC_;
    const unsigned short* Vbase = Vt + (size_t)b * RC_ * N_;
    unsigned short* Klw = &Kl[wg][0];
    unsigned short* Vlw = &Vl[wg][0];
    unsigned short* Plw = &Pl[wv_ * 16 * VS];

    uint4 kr[4], vr[4];
    // group tile index range: [wg*32, wg*32+32)
    #define LOAD_KV(kt_)  do {                                                   \
        const unsigned short* ksrc = Kbase + (size_t)(kt_) * 64 * RC_;           \
        _Pragma("unroll")                                                        \
        for (int j = 0; j < 4; ++j) {                                            \
            int c = tg + j * 256;                                                \
            kr[j] = *(const uint4*)&ksrc[(c >> 4) * RC_ + (c & 15) * 8];         \
        }                                                                        \
        const unsigned short* vsrc = Vbase + (size_t)(kt_) * 64;                 \
        _Pragma("unroll")                                                        \
        for (int j = 0; j < 4; ++j) {                                            \
            int c = tg + j * 256;                                                \
            vr[j] = *(const uint4*)&vsrc[(size_t)(c >> 3) * N_ + (c & 7) * 8];   \
        }                                                                        \
    } while (0)
    #define WRITE_KV() do {                                                      \
        _Pragma("unroll")                                                        \
        for (int j = 0; j < 4; ++j) {                                            \
            int c = tg + j * 256;                                                \
            *(uint4*)&Klw[(c >> 4) * QS + (c & 15) * 8] = kr[j];                 \
        }                                                                        \
        _Pragma("unroll")                                                        \
        for (int j = 0; j < 4; ++j) {                                            \
            int c = tg + j * 256;                                                \
            *(uint4*)&Vlw[(c >> 3) * VS + (c & 7) * 8] = vr[j];                  \
        }                                                                        \
    } while (0)

    LOAD_KV(wg * 32);
    WRITE_KV();
    __syncthreads();

    // hoist loop-invariant Q fragments (16 VGPR)
    u16x8 qa[4];
    #pragma unroll
    for (int ks = 0; ks < 4; ++ks)
        qa[ks] = *(const u16x8*)&Ql[(wig * 16 + q16) * QS + ks * 32 + g * 8];

    f32x4 acc_o[8];
    #pragma unroll
    for (int rf = 0; rf < 8; ++rf) acc_o[rf] = (f32x4){0.f, 0.f, 0.f, 0.f};
    float m_i[4], l_i[4];
    #pragma unroll
    for (int i = 0; i < 4; ++i) { m_i[i] = -1e30f; l_i[i] = 0.f; }

    for (int kk = 0; kk < 32; ++kk) {
        // prefetch next tile into registers (async; consumed after the barrier)
        if (kk < 31) LOAD_KV(wg * 32 + kk + 1);

        // S = Q K^T.  s_acc[jf][i] = S[q=wig*16+g*4+i][k=jf*16+q16]
        f32x4 s_acc[4];
        #pragma unroll
        for (int jf = 0; jf < 4; ++jf) s_acc[jf] = (f32x4){0.f, 0.f, 0.f, 0.f};
        #pragma unroll
        for (int jf = 0; jf < 4; ++jf) {
            #pragma unroll
            for (int ks = 0; ks < 4; ++ks) {
                u16x8 bf = *(const u16x8*)&Klw[(jf * 16 + q16) * QS + ks * 32 + g * 8];
                s_acc[jf] = mfma16(qa[ks], bf, s_acc[jf]);
            }
        }

        // online softmax (DPP reductions over the 16-lane row group)
        float alpha[4];
        #pragma unroll
        for (int i = 0; i < 4; ++i) {
            float mx = fmaxf(fmaxf(s_acc[0][i], s_acc[1][i]),
                             fmaxf(s_acc[2][i], s_acc[3][i]));
            mx = red16_max(mx);
            float m_new = fmaxf(m_i[i], mx);
            alpha[i] = __expf(m_i[i] - m_new);
            m_i[i] = m_new;
            float rs = 0.f;
            #pragma unroll
            for (int jf = 0; jf < 4; ++jf) {
                float p = __expf(s_acc[jf][i] - m_new);
                s_acc[jf][i] = p;
                rs += p;
            }
            rs = red16_sum(rs);
            l_i[i] = l_i[i] * alpha[i] + rs;
        }

        // stage P (bf16) into this wave's own region (no barrier needed); rescale O
        #pragma unroll
        for (int jf = 0; jf < 4; ++jf)
            #pragma unroll
            for (int i = 0; i < 4; ++i)
                Plw[(g * 4 + i) * VS + jf * 16 + q16] = f2bf(s_acc[jf][i]);
        #pragma unroll
        for (int rf = 0; rf < 8; ++rf)
            #pragma unroll
            for (int i = 0; i < 4; ++i)
                acc_o[rf][i] *= alpha[i];

        // O += P @ V
        u16x8 pa[2];
        #pragma unroll
        for (int ks = 0; ks < 2; ++ks)
            pa[ks] = *(const u16x8*)&Plw[q16 * VS + ks * 32 + g * 8];
        #pragma unroll
        for (int rf = 0; rf < 8; ++rf) {
            #pragma unroll
            for (int ks = 0; ks < 2; ++ks) {
                u16x8 vb = *(const u16x8*)&Vlw[(rf * 16 + q16) * VS + ks * 32 + g * 8];
                acc_o[rf] = mfma16(pa[ks], vb, acc_o[rf]);
            }
        }

        __syncthreads();                 // all waves done reading Kl/Vl
        if (kk < 31) WRITE_KV();         // commit prefetched tile
        __syncthreads();                 // staged
    }

    // ---- merge the two KV-halves (group 1 -> LDS, group 0 combines & stores) ----
    float* Mf  = (float*)&Kl[0][0];      // 64 x 136 f32 partial O   (34816 B, fits exactly)
    float* MLf = (float*)&Vl[0][0];      // 64 x {m,l}
    if (wg == 1) {
        #pragma unroll
        for (int rf = 0; rf < 8; ++rf)
            #pragma unroll
            for (int i = 0; i < 4; ++i)
                Mf[(wig * 16 + g * 4 + i) * 136 + rf * 16 + q16] = acc_o[rf][i];
        if (q16 == 0) {
            #pragma unroll
            for (int i = 0; i < 4; ++i) {
                int r = wig * 16 + g * 4 + i;
                MLf[r * 2]     = m_i[i];
                MLf[r * 2 + 1] = l_i[i];
            }
        }
    }
    __syncthreads();
    if (wg == 0) {
        #pragma unroll
        for (int i = 0; i < 4; ++i) {
            int r = wig * 16 + g * 4 + i;
            float m1 = MLf[r * 2], l1 = MLf[r * 2 + 1];
            float ms = fmaxf(m_i[i], m1);
            float e0 = __expf(m_i[i] - ms), e1 = __expf(m1 - ms);
            float inv = 1.f / (l_i[i] * e0 + l1 * e1);
            int n = n0 + r;
            #pragma unroll
            for (int rf = 0; rf < 8; ++rf) {
                float o = (acc_o[rf][i] * e0 + Mf[r * 136 + rf * 16 + q16] * e1) * inv;
                Ob[((size_t)b * N_ + n) * RC_ + rf * 16 + q16] = f2bf(o);
            }
        }
    }
    #undef LOAD_KV
    #undef WRITE_KV
}

// ---------------- kernel 3: output projection + residual ----------------
__global__ __launch_bounds__(256) void k_out(
    const unsigned short* __restrict__ Ob, const unsigned short* __restrict__ wobf,
    const float* __restrict__ bo, const float* __restrict__ x,
    const float* __restrict__ gamma, float* __restrict__ out)
{
    __shared__ unsigned short Ol[64 * QS];
    const int b  = blockIdx.z;
    const int c0 = blockIdx.y * 128;
    const int n0 = blockIdx.x * 64;
    const int t  = threadIdx.x;
    const int lane = t & 63, wv_ = t >> 6;
    const int g = lane >> 4, q16 = lane & 15;

    {
        const unsigned short* src = Ob + ((size_t)b * N_ + n0) * RC_;
        #pragma unroll
        for (int p = 0; p < 4; ++p) {
            int row = p * 16 + (t >> 4);
            int s = (t & 15) * 8;
            *(u16x8*)&Ol[row * QS + s] = *(const u16x8*)&src[row * RC_ + s];
        }
    }
    __syncthreads();

    f32x4 acc[2][4];
    #pragma unroll
    for (int cf = 0; cf < 2; ++cf)
        #pragma unroll
        for (int nf = 0; nf < 4; ++nf)
            acc[cf][nf] = (f32x4){0.f, 0.f, 0.f, 0.f};

    const int cw = c0 + wv_ * 32;
    #pragma unroll
    for (int ks = 0; ks < 4; ++ks) {
        u16x8 b8[4];
        #pragma unroll
        for (int nf = 0; nf < 4; ++nf)
            b8[nf] = *(const u16x8*)&Ol[(nf * 16 + q16) * QS + ks * 32 + g * 8];
        #pragma unroll
        for (int cf = 0; cf < 2; ++cf) {
            u16x8 a8 = *(const u16x8*)&wobf[(size_t)(cw + cf * 16 + q16) * 128 + ks * 32 + g * 8];
            #pragma unroll
            for (int nf = 0; nf < 4; ++nf)
                acc[cf][nf] = mfma16(a8, b8[nf], acc[cf][nf]);
        }
    }

    float gm = gamma[0];
    #pragma unroll
    for (int cf = 0; cf < 2; ++cf) {
        #pragma unroll
        for (int i = 0; i < 4; ++i) {
            int c = cw + cf * 16 + g * 4 + i;
            float bias = bo[c];
            #pragma unroll
            for (int nf = 0; nf < 4; ++nf) {
                int n = n0 + nf * 16 + q16;
                size_t idx = ((size_t)b * C_ + c) * N_ + n;
                out[idx] = gm * (acc[cf][nf][i] + bias) + x[idx];
            }
        }
    }
}

extern "C" void kernel_launch(void* const* d_in, const int* in_sizes, int n_in,
                              void* d_out, int out_size, void* d_ws, size_t ws_size,
                              hipStream_t stream) {
    const float* x     = (const float*)d_in[0];
    const float* wq    = (const float*)d_in[1];
    const float* bq    = (const float*)d_in[2];
    const float* wk    = (const float*)d_in[3];
    const float* bk    = (const float*)d_in[4];
    const float* wv    = (const float*)d_in[5];
    const float* bv    = (const float*)d_in[6];
    const float* wo    = (const float*)d_in[7];
    const float* bo    = (const float*)d_in[8];
    const float* gamma = (const float*)d_in[9];
    float* out = (float*)d_out;

    unsigned short* ws = (unsigned short*)d_ws;
    unsigned short* wbf  = ws;                 // wq,wk,wv (3*32768), wo at +98304
    unsigned short* wobf = ws + 98304;
    unsigned short* Qb   = ws + 131072;        // B*N*RC = 2097152 shorts each
    unsigned short* Kb   = Qb + 2097152;
    unsigned short* Vt   = Kb + 2097152;
    unsigned short* Ob   = Vt + 2097152;

    k_cvtw<<<512, 256, 0, stream>>>(wq, wk, wv, wo, ws);
    dim3 g1(64, 4);
    k_qkv<<<g1, 256, 0, stream>>>(x, wbf, bq, bk, bv, Qb, Kb, Vt);
    dim3 g2(64, 4);
    k_attn<<<g2, 512, 0, stream>>>(Qb, Kb, Vt, Ob);
    dim3 g3(64, 2, 4);
    k_out<<<g3, 256, 0, stream>>>(Ob, wobf, bo, x, gamma, out);
}

// Round 3
// 133.862 us; speedup vs baseline: 1.3972x; 1.3972x over previous
//
#include <hip/hip_runtime.h>
#include <hip/hip_bf16.h>

// SelfAttentionBlock: B=4, C=256, RC=128, H=W=64 (N=4096)
// Round 3: k_attn rewritten — 8 waves = 2 q-waves(32 rows each) x 4 KV-groups (in-block
// split-KV, KVBLK=32), conflict-free swizzled/padded LDS, Q in registers, 4-way LDS merge.

#define B_   4
#define C_   256
#define RC_  128
#define N_   4096
#define SCALE 0.08838834764831845f  // 1/sqrt(128)

typedef __bf16 bf16x8 __attribute__((ext_vector_type(8)));
typedef unsigned short u16x8 __attribute__((ext_vector_type(8)));
typedef float f32x4 __attribute__((ext_vector_type(4)));

static __device__ __forceinline__ unsigned short f2bf(float f) {
    unsigned int u = __builtin_bit_cast(unsigned int, f);
    u += 0x7fffu + ((u >> 16) & 1u);   // round-to-nearest-even
    return (unsigned short)(u >> 16);
}

static __device__ __forceinline__ f32x4 mfma16(u16x8 a, u16x8 b, f32x4 c) {
    return __builtin_amdgcn_mfma_f32_16x16x32_bf16(
        __builtin_bit_cast(bf16x8, a), __builtin_bit_cast(bf16x8, b), c, 0, 0, 0);
}

template<int CTRL>
static __device__ __forceinline__ float dppf(float x) {
    int r = __builtin_amdgcn_update_dpp(0, __builtin_bit_cast(int, x), CTRL, 0xf, 0xf, true);
    return __builtin_bit_cast(float, r);
}
static __device__ __forceinline__ float red16_max(float v) {
    v = fmaxf(v, dppf<0xB1>(v));   // quad_perm xor1
    v = fmaxf(v, dppf<0x4E>(v));   // quad_perm xor2
    v = fmaxf(v, dppf<0x124>(v));  // row_ror:4
    v = fmaxf(v, dppf<0x128>(v));  // row_ror:8
    return v;
}
static __device__ __forceinline__ float red16_sum(float v) {
    v += dppf<0xB1>(v);
    v += dppf<0x4E>(v);
    v += dppf<0x124>(v);
    v += dppf<0x128>(v);
    return v;
}

// ---------------- kernel 0: convert weights to bf16 ----------------
__global__ __launch_bounds__(256) void k_cvtw(
    const float* __restrict__ wq, const float* __restrict__ wk,
    const float* __restrict__ wv, const float* __restrict__ wo,
    unsigned short* __restrict__ ws)
{
    int i = blockIdx.x * 256 + threadIdx.x;  // 0..131071
    const float* src; int off;
    if (i < 32768)       { src = wq; off = 0; }
    else if (i < 65536)  { src = wk; off = 32768; }
    else if (i < 98304)  { src = wv; off = 65536; }
    else                 { src = wo; off = 98304; }
    int j = i - off;
    ws[off + j] = f2bf(src[j]);
}

// ---------------- kernel 1: QKV projection ----------------
#define K1_LDA 264  // 256 + 8 pad (shorts)

__global__ __launch_bounds__(256) void k_qkv(
    const float* __restrict__ x, const unsigned short* __restrict__ wbf,
    const float* __restrict__ bq, const float* __restrict__ bk, const float* __restrict__ bv,
    unsigned short* __restrict__ Qb, unsigned short* __restrict__ Kb,
    unsigned short* __restrict__ Vt)
{
    __shared__ unsigned short lds[64 * K1_LDA];
    const int b  = blockIdx.y;
    const int n0 = blockIdx.x * 64;
    const int t  = threadIdx.x;
    const int lane = t & 63, wv_ = t >> 6;
    const int g = lane >> 4, q16 = lane & 15;

    {
        const float* xb = x + ((size_t)b * C_ * N_) + n0 + lane;
        #pragma unroll
        for (int it = 0; it < 8; ++it) {
            int c0 = wv_ * 64 + it * 8;
            u16x8 v;
            #pragma unroll
            for (int e = 0; e < 8; ++e)
                v[e] = f2bf(xb[(size_t)(c0 + e) * N_]);
            *(u16x8*)&lds[lane * K1_LDA + c0] = v;
        }
    }
    __syncthreads();

    f32x4 acc[3][2][4];
    #pragma unroll
    for (int tq = 0; tq < 3; ++tq)
        #pragma unroll
        for (int r2 = 0; r2 < 2; ++r2)
            #pragma unroll
            for (int nf = 0; nf < 4; ++nf)
                acc[tq][r2][nf] = (f32x4){0.f, 0.f, 0.f, 0.f};

    const int rbase = wv_ * 32;
    #pragma unroll
    for (int ks = 0; ks < 8; ++ks) {
        u16x8 a[4];
        #pragma unroll
        for (int nf = 0; nf < 4; ++nf)
            a[nf] = *(const u16x8*)&lds[(nf * 16 + q16) * K1_LDA + ks * 32 + g * 8];
        #pragma unroll
        for (int tq = 0; tq < 3; ++tq) {
            const unsigned short* w = wbf + tq * 32768;
            #pragma unroll
            for (int r2 = 0; r2 < 2; ++r2) {
                u16x8 bf = *(const u16x8*)&w[(size_t)(rbase + r2 * 16 + q16) * 256 + ks * 32 + g * 8];
                #pragma unroll
                for (int nf = 0; nf < 4; ++nf)
                    acc[tq][r2][nf] = mfma16(a[nf], bf, acc[tq][r2][nf]);
            }
        }
    }

    #pragma unroll
    for (int r2 = 0; r2 < 2; ++r2) {
        int r = rbase + r2 * 16 + q16;
        float biasq = bq[r], biask = bk[r];
        #pragma unroll
        for (int nf = 0; nf < 4; ++nf) {
            #pragma unroll
            for (int i = 0; i < 4; ++i) {
                int n = n0 + nf * 16 + g * 4 + i;
                size_t idx = ((size_t)b * N_ + n) * RC_ + r;
                Qb[idx] = f2bf((acc[0][r2][nf][i] + biasq) * SCALE);
                Kb[idx] = f2bf(acc[1][r2][nf][i] + biask);
            }
        }
    }

    __syncthreads();
    #pragma unroll
    for (int r2 = 0; r2 < 2; ++r2) {
        int r = rbase + r2 * 16 + q16;
        float biasv = bv[r];
        #pragma unroll
        for (int nf = 0; nf < 4; ++nf)
            #pragma unroll
            for (int i = 0; i < 4; ++i)
                lds[r * 72 + nf * 16 + g * 4 + i] = f2bf(acc[2][r2][nf][i] + biasv);
    }
    __syncthreads();
    #pragma unroll
    for (int it = 0; it < 4; ++it) {
        int r = it * 32 + (t >> 3);
        int s = (t & 7) * 8;
        u16x8 v = *(const u16x8*)&lds[r * 72 + s];
        *(u16x8*)&Vt[((size_t)b * RC_ + r) * N_ + n0 + s] = v;
    }
}

// ---------------- kernel 2: flash attention ----------------
// 8 waves: qw = wv&1 (32 q-rows each), grp = wv>>1 (KV quarter: 1024 keys, 32 tiles of 32).
// LDS (shorts): K[grp] 32x128 XOR-swizzled @ grp*4096            [0,16384)
//               V[grp] 128x40 padded       @ 16384+grp*5120      [16384,36864)
//               P[wv]  32x40 padded        @ 36864+wv*1280       [36864,47104)
//               merge U (f32, reuses [0,50688))  ml (f32) @ 50688 [50688,51712)
__global__ __launch_bounds__(512, 2) void k_attn(
    const unsigned short* __restrict__ Qb, const unsigned short* __restrict__ Kb,
    const unsigned short* __restrict__ Vt, unsigned short* __restrict__ Ob)
{
    __shared__ __align__(16) unsigned short smem[51712];   // 101 KB
    const int b  = blockIdx.y;
    const int n0 = blockIdx.x * 64;
    const int t  = threadIdx.x;
    const int lane = t & 63, wv_ = t >> 6;
    const int qw = wv_ & 1, grp = wv_ >> 1;
    const int g = lane >> 4, q16 = lane & 15;
    const int c = qw * 64 + lane;            // staging id within KV group (0..127)

    unsigned short* Kl = &smem[grp * 4096];
    unsigned short* Vl = &smem[16384 + grp * 5120];
    unsigned short* Pl = &smem[36864 + wv_ * 1280];
    float* mlf = (float*)&smem[50688];       // [64 rows][4 grp][2]

    // Q fragments straight from global (L2-resident)
    u16x8 qa[2][4];
    {
        const unsigned short* qsrc = Qb + ((size_t)b * N_ + n0 + qw * 32) * RC_;
        #pragma unroll
        for (int rf = 0; rf < 2; ++rf)
            #pragma unroll
            for (int ks = 0; ks < 4; ++ks)
                qa[rf][ks] = *(const u16x8*)&qsrc[(rf * 16 + q16) * RC_ + ks * 32 + g * 8];
    }

    f32x4 acc_o[2][8];
    #pragma unroll
    for (int rf = 0; rf < 2; ++rf)
        #pragma unroll
        for (int df = 0; df < 8; ++df)
            acc_o[rf][df] = (f32x4){0.f, 0.f, 0.f, 0.f};
    float m_i[2][4], l_i[2][4];
    #pragma unroll
    for (int rf = 0; rf < 2; ++rf)
        #pragma unroll
        for (int i = 0; i < 4; ++i) { m_i[rf][i] = -1e30f; l_i[rf][i] = 0.f; }

    const unsigned short* Kbase = Kb + (size_t)b * N_ * RC_;
    const unsigned short* Vbase = Vt + (size_t)b * RC_ * N_;

    for (int kk = 0; kk < 32; ++kk) {
        const int kbase = grp * 1024 + kk * 32;
        __syncthreads();   // previous window's reads done
        // stage K tile [32][128], XOR-swizzled chunks (chunk ^= row&7)
        #pragma unroll
        for (int j = 0; j < 4; ++j) {
            int id = c + j * 128;
            int row = id >> 4, ch = id & 15;
            uint4 v = *(const uint4*)&Kbase[(size_t)(kbase + row) * RC_ + ch * 8];
            *(uint4*)&Kl[row * 128 + ((ch ^ (row & 7)) * 8)] = v;
        }
        // stage V tile [128][40] (pad 8 shorts; 20-dword rows are conflict-free)
        #pragma unroll
        for (int j = 0; j < 4; ++j) {
            int id = c + j * 128;
            int d = id >> 2, kc = id & 3;
            uint4 v = *(const uint4*)&Vbase[(size_t)d * N_ + kbase + kc * 8];
            *(uint4*)&Vl[d * 40 + kc * 8] = v;
        }
        __syncthreads();

        // S = Q K^T.  s[rf][jf][i] = S[q = qw*32+rf*16+g*4+i][k = jf*16+q16]
        f32x4 s[2][2];
        #pragma unroll
        for (int rf = 0; rf < 2; ++rf)
            #pragma unroll
            for (int jf = 0; jf < 2; ++jf)
                s[rf][jf] = (f32x4){0.f, 0.f, 0.f, 0.f};
        #pragma unroll
        for (int jf = 0; jf < 2; ++jf) {
            #pragma unroll
            for (int ks = 0; ks < 4; ++ks) {
                u16x8 kf = *(const u16x8*)&Kl[(jf * 16 + q16) * 128 + (((4 * ks + g) ^ (q16 & 7)) * 8)];
                s[0][jf] = mfma16(qa[0][ks], kf, s[0][jf]);
                s[1][jf] = mfma16(qa[1][ks], kf, s[1][jf]);
            }
        }

        // online softmax per row-frag (DPP reduce over 16-lane row group)
        float alpha[2][4];
        #pragma unroll
        for (int rf = 0; rf < 2; ++rf)
            #pragma unroll
            for (int i = 0; i < 4; ++i) {
                float mx = red16_max(fmaxf(s[rf][0][i], s[rf][1][i]));
                float m_new = fmaxf(m_i[rf][i], mx);
                alpha[rf][i] = __expf(m_i[rf][i] - m_new);
                m_i[rf][i] = m_new;
                float p0 = __expf(s[rf][0][i] - m_new);
                float p1 = __expf(s[rf][1][i] - m_new);
                s[rf][0][i] = p0; s[rf][1][i] = p1;
                float rs = red16_sum(p0 + p1);
                l_i[rf][i] = l_i[rf][i] * alpha[rf][i] + rs;
            }

        // stage P (bf16) [32][40] per wave
        #pragma unroll
        for (int rf = 0; rf < 2; ++rf)
            #pragma unroll
            for (int jf = 0; jf < 2; ++jf)
                #pragma unroll
                for (int i = 0; i < 4; ++i)
                    Pl[(rf * 16 + g * 4 + i) * 40 + jf * 16 + q16] = f2bf(s[rf][jf][i]);

        // rescale O
        #pragma unroll
        for (int rf = 0; rf < 2; ++rf)
            #pragma unroll
            for (int df = 0; df < 8; ++df)
                #pragma unroll
                for (int i = 0; i < 4; ++i)
                    acc_o[rf][df][i] *= alpha[rf][i];

        // O += P @ V   (V fragment shared across both row-frags)
        u16x8 pa[2];
        #pragma unroll
        for (int rf = 0; rf < 2; ++rf)
            pa[rf] = *(const u16x8*)&Pl[(rf * 16 + q16) * 40 + g * 8];
        #pragma unroll
        for (int df = 0; df < 8; ++df) {
            u16x8 vb = *(const u16x8*)&Vl[(df * 16 + q16) * 40 + g * 8];
            acc_o[0][df] = mfma16(pa[0], vb, acc_o[0][df]);
            acc_o[1][df] = mfma16(pa[1], vb, acc_o[1][df]);
        }
    }

    // ---- 4-way merge: groups 1-3 dump unnormalized U (f32) + (m,l) to LDS ----
    __syncthreads();
    if (grp > 0) {
        float* U = (float*)&smem[0] + ((grp - 1) * 2 + qw) * (32 * 132);
        #pragma unroll
        for (int rf = 0; rf < 2; ++rf)
            #pragma unroll
            for (int df = 0; df < 8; ++df)
                #pragma unroll
                for (int i = 0; i < 4; ++i)
                    U[(rf * 16 + g * 4 + i) * 132 + df * 16 + q16] = acc_o[rf][df][i];
        if (q16 == 0) {
            #pragma unroll
            for (int rf = 0; rf < 2; ++rf)
                #pragma unroll
                for (int i = 0; i < 4; ++i) {
                    int row = qw * 32 + rf * 16 + g * 4 + i;
                    mlf[row * 8 + grp * 2]     = m_i[rf][i];
                    mlf[row * 8 + grp * 2 + 1] = l_i[rf][i];
                }
        }
    }
    __syncthreads();
    if (grp == 0) {
        const float* U1 = (float*)&smem[0] + (0 * 2 + qw) * (32 * 132);
        const float* U2 = (float*)&smem[0] + (1 * 2 + qw) * (32 * 132);
        const float* U3 = (float*)&smem[0] + (2 * 2 + qw) * (32 * 132);
        #pragma unroll
        for (int rf = 0; rf < 2; ++rf)
            #pragma unroll
            for (int i = 0; i < 4; ++i) {
                int rloc = rf * 16 + g * 4 + i;
                int rabs = qw * 32 + rloc;
                float m1 = mlf[rabs * 8 + 2], l1 = mlf[rabs * 8 + 3];
                float m2 = mlf[rabs * 8 + 4], l2 = mlf[rabs * 8 + 5];
                float m3 = mlf[rabs * 8 + 6], l3 = mlf[rabs * 8 + 7];
                float ms = fmaxf(fmaxf(m_i[rf][i], m1), fmaxf(m2, m3));
                float e0 = __expf(m_i[rf][i] - ms);
                float e1 = __expf(m1 - ms);
                float e2 = __expf(m2 - ms);
                float e3 = __expf(m3 - ms);
                float inv = 1.f / (l_i[rf][i] * e0 + l1 * e1 + l2 * e2 + l3 * e3);
                #pragma unroll
                for (int df = 0; df < 8; ++df) {
                    float o = acc_o[rf][df][i] * e0
                            + U1[rloc * 132 + df * 16 + q16] * e1
                            + U2[rloc * 132 + df * 16 + q16] * e2
                            + U3[rloc * 132 + df * 16 + q16] * e3;
                    Ob[((size_t)b * N_ + n0 + qw * 32 + rloc) * RC_ + df * 16 + q16] = f2bf(o * inv);
                }
            }
    }
}

// ---------------- kernel 3: output projection + residual ----------------
#define QS 136  // 128 + 8 pad (shorts)

__global__ __launch_bounds__(256) void k_out(
    const unsigned short* __restrict__ Ob, const unsigned short* __restrict__ wobf,
    const float* __restrict__ bo, const float* __restrict__ x,
    const float* __restrict__ gamma, float* __restrict__ out)
{
    __shared__ unsigned short Ol[64 * QS];
    const int b  = blockIdx.z;
    const int c0 = blockIdx.y * 128;
    const int n0 = blockIdx.x * 64;
    const int t  = threadIdx.x;
    const int lane = t & 63, wv_ = t >> 6;
    const int g = lane >> 4, q16 = lane & 15;

    {
        const unsigned short* src = Ob + ((size_t)b * N_ + n0) * RC_;
        #pragma unroll
        for (int p = 0; p < 4; ++p) {
            int row = p * 16 + (t >> 4);
            int s = (t & 15) * 8;
            *(u16x8*)&Ol[row * QS + s] = *(const u16x8*)&src[row * RC_ + s];
        }
    }
    __syncthreads();

    f32x4 acc[2][4];
    #pragma unroll
    for (int cf = 0; cf < 2; ++cf)
        #pragma unroll
        for (int nf = 0; nf < 4; ++nf)
            acc[cf][nf] = (f32x4){0.f, 0.f, 0.f, 0.f};

    const int cw = c0 + wv_ * 32;
    #pragma unroll
    for (int ks = 0; ks < 4; ++ks) {
        u16x8 b8[4];
        #pragma unroll
        for (int nf = 0; nf < 4; ++nf)
            b8[nf] = *(const u16x8*)&Ol[(nf * 16 + q16) * QS + ks * 32 + g * 8];
        #pragma unroll
        for (int cf = 0; cf < 2; ++cf) {
            u16x8 a8 = *(const u16x8*)&wobf[(size_t)(cw + cf * 16 + q16) * 128 + ks * 32 + g * 8];
            #pragma unroll
            for (int nf = 0; nf < 4; ++nf)
                acc[cf][nf] = mfma16(a8, b8[nf], acc[cf][nf]);
        }
    }

    float gm = gamma[0];
    #pragma unroll
    for (int cf = 0; cf < 2; ++cf) {
        #pragma unroll
        for (int i = 0; i < 4; ++i) {
            int c = cw + cf * 16 + g * 4 + i;
            float bias = bo[c];
            #pragma unroll
            for (int nf = 0; nf < 4; ++nf) {
                int n = n0 + nf * 16 + q16;
                size_t idx = ((size_t)b * C_ + c) * N_ + n;
                out[idx] = gm * (acc[cf][nf][i] + bias) + x[idx];
            }
        }
    }
}

extern "C" void kernel_launch(void* const* d_in, const int* in_sizes, int n_in,
                              void* d_out, int out_size, void* d_ws, size_t ws_size,
                              hipStream_t stream) {
    const float* x     = (const float*)d_in[0];
    const float* wq    = (const float*)d_in[1];
    const float* bq    = (const float*)d_in[2];
    const float* wk    = (const float*)d_in[3];
    const float* bk    = (const float*)d_in[4];
    const float* wv    = (const float*)d_in[5];
    const float* bv    = (const float*)d_in[6];
    const float* wo    = (const float*)d_in[7];
    const float* bo    = (const float*)d_in[8];
    const float* gamma = (const float*)d_in[9];
    float* out = (float*)d_out;

    unsigned short* ws = (unsigned short*)d_ws;
    unsigned short* wbf  = ws;                 // wq,wk,wv (3*32768), wo at +98304
    unsigned short* wobf = ws + 98304;
    unsigned short* Qb   = ws + 131072;        // B*N*RC = 2097152 shorts each
    unsigned short* Kb   = Qb + 2097152;
    unsigned short* Vt   = Kb + 2097152;
    unsigned short* Ob   = Vt + 2097152;

    k_cvtw<<<512, 256, 0, stream>>>(wq, wk, wv, wo, ws);
    dim3 g1(64, 4);
    k_qkv<<<g1, 256, 0, stream>>>(x, wbf, bq, bk, bv, Qb, Kb, Vt);
    dim3 g2(64, 4);
    k_attn<<<g2, 512, 0, stream>>>(Qb, Kb, Vt, Ob);
    dim3 g3(64, 2, 4);
    k_out<<<g3, 256, 0, stream>>>(Ob, wobf, bo, x, gamma, out);
}